// Round 3
// baseline (4461.570 us; speedup 1.0000x reference)
//
#include <hip/hip_runtime.h>
#include <hip/hip_bf16.h>

// Problem constants (MultiHeadAttention_14508399526473)
// Inputs fp32 (per reference). Outputs fp32: [out (B,S,D) | attn (B,H,S,S)].
#define B_ 2
#define S_ 2048
#define D_ 1024
#define H_ 16
#define DH_ 64
#define EPS_ 1e-6f

// ---------------------------------------------------------------------------
// Tiled GEMM: C[M,N] = A[M,K] @ W[K,N] + bias[N] (+ residual[M,N] optional)
// All fp32. Block (16,16), 64x64 tile, 4x4 per thread, K-chunks of 16.
// M,N,K % 64 == 0.
// ---------------------------------------------------------------------------
__global__ __launch_bounds__(256) void gemm_bias_kernel(
    const float* __restrict__ A, const float* __restrict__ W,
    const float* __restrict__ bias, const float* __restrict__ residual,
    float* __restrict__ C, int M, int N, int K)
{
    __shared__ float As[64][17];   // [row][k], pad to kill bank conflicts
    __shared__ float Ws[16][64];   // [k][col]

    const int tx = threadIdx.x, ty = threadIdx.y;
    const int tid = ty * 16 + tx;
    const int row0 = blockIdx.y * 64;
    const int col0 = blockIdx.x * 64;

    float c[4][4];
#pragma unroll
    for (int i = 0; i < 4; ++i)
#pragma unroll
        for (int j = 0; j < 4; ++j) c[i][j] = 0.f;

    for (int k0 = 0; k0 < K; k0 += 16) {
#pragma unroll
        for (int l = 0; l < 4; ++l) {           // A tile: 64 rows x 16 k
            int idx = tid + l * 256;            // 0..1023
            int r = idx >> 4, kk = idx & 15;
            As[r][kk] = A[(size_t)(row0 + r) * K + k0 + kk];
        }
#pragma unroll
        for (int l = 0; l < 4; ++l) {           // W tile: 16 k x 64 cols
            int idx = tid + l * 256;
            int kk = idx >> 6, cc = idx & 63;
            Ws[kk][cc] = W[(size_t)(k0 + kk) * N + col0 + cc];
        }
        __syncthreads();
#pragma unroll
        for (int kk = 0; kk < 16; ++kk) {
            float a[4], w[4];
#pragma unroll
            for (int i = 0; i < 4; ++i) a[i] = As[ty + i * 16][kk];
#pragma unroll
            for (int j = 0; j < 4; ++j) w[j] = Ws[kk][tx + j * 16];
#pragma unroll
            for (int i = 0; i < 4; ++i)
#pragma unroll
                for (int j = 0; j < 4; ++j) c[i][j] += a[i] * w[j];
        }
        __syncthreads();
    }

#pragma unroll
    for (int i = 0; i < 4; ++i) {
        int r = row0 + ty + i * 16;
#pragma unroll
        for (int j = 0; j < 4; ++j) {
            int cc = col0 + tx + j * 16;
            float v = c[i][j] + bias[cc];
            if (residual) v += residual[(size_t)r * N + cc];
            C[(size_t)r * N + cc] = v;
        }
    }
}

// ---------------------------------------------------------------------------
// Attention: one block per (q-row, b*H+h). Full-row softmax in LDS, writes
// fp32 attn row to d_out and fp32 ctx (B,S,D layout) to ws.
// ---------------------------------------------------------------------------
__global__ __launch_bounds__(256) void attn_kernel(
    const float* __restrict__ Q, const float* __restrict__ Kmat,
    const float* __restrict__ V,
    float* __restrict__ attn_out, float* __restrict__ ctx)
{
    const int qi = blockIdx.x;
    const int bh = blockIdx.y;           // b*H + h
    const int b  = bh / H_, h = bh % H_;
    const int tid = threadIdx.x;

    __shared__ float qs[DH_];
    __shared__ float lg[S_];
    __shared__ float red[256];

    const size_t qk_base = ((size_t)b * S_) * D_ + h * DH_;
    if (tid < DH_) qs[tid] = Q[qk_base + (size_t)qi * D_ + tid] * 0.125f; // 1/sqrt(64)
    __syncthreads();

    const int len = qi + 1;              // causal: keys 0..qi valid
    const float4* q4 = (const float4*)qs;

    float lmax = -INFINITY;
    for (int j = tid; j < len; j += 256) {
        const float4* k4 = (const float4*)(Kmat + qk_base + (size_t)j * D_);
        float acc = 0.f;
#pragma unroll
        for (int t = 0; t < DH_ / 4; ++t) {
            float4 a = q4[t], k = k4[t];
            acc += a.x * k.x + a.y * k.y + a.z * k.z + a.w * k.w;
        }
        lg[j] = acc;
        lmax = fmaxf(lmax, acc);
    }
    red[tid] = lmax;
    __syncthreads();
    for (int s = 128; s > 0; s >>= 1) {
        if (tid < s) red[tid] = fmaxf(red[tid], red[tid + s]);
        __syncthreads();
    }
    const float m = red[0];
    __syncthreads();

    float lsum = 0.f;
    for (int j = tid; j < len; j += 256) {
        float e = __expf(lg[j] - m);
        lg[j] = e;
        lsum += e;
    }
    red[tid] = lsum;
    __syncthreads();
    for (int s = 128; s > 0; s >>= 1) {
        if (tid < s) red[tid] += red[tid + s];
        __syncthreads();
    }
    const float inv = 1.f / red[0];
    __syncthreads();

    // attn row (masked tail = exact 0, matching exp(-1e4 - m) fp32 underflow)
    float* arow = attn_out + ((size_t)bh * S_ + qi) * S_;
    for (int j = tid; j < S_; j += 256) {
        float p = (j < len) ? lg[j] * inv : 0.f;
        arow[j] = p;
    }

    // ctx[d] = inv * sum_j e_j * V[j][d]; 4 groups of 64 lanes over j
    const int d = tid & 63, g = tid >> 6;
    float acc = 0.f;
    for (int j = g; j < len; j += 4)
        acc += lg[j] * V[qk_base + (size_t)j * D_ + d];
    red[tid] = acc;
    __syncthreads();
    if (tid < 64) {
        float s = red[tid] + red[64 + tid] + red[128 + tid] + red[192 + tid];
        ctx[((size_t)b * S_ + qi) * D_ + h * DH_ + tid] = s * inv;
    }
}

// ---------------------------------------------------------------------------
// Row LayerNorm: one block per row of [B*S, D], fp32 in, fp32 out.
// ---------------------------------------------------------------------------
__global__ __launch_bounds__(256) void ln_kernel(
    const float* __restrict__ X, const float* __restrict__ gamma,
    const float* __restrict__ beta, float* __restrict__ out)
{
    const int row = blockIdx.x;
    const int tid = threadIdx.x;
    const float* x = X + (size_t)row * D_;
    __shared__ float red[256];

    float s = 0.f;
    for (int i = tid; i < D_; i += 256) s += x[i];
    red[tid] = s;
    __syncthreads();
    for (int t = 128; t > 0; t >>= 1) {
        if (tid < t) red[tid] += red[tid + t];
        __syncthreads();
    }
    const float mu = red[0] * (1.f / D_);
    __syncthreads();

    float v = 0.f;
    for (int i = tid; i < D_; i += 256) {
        float t = x[i] - mu;
        v += t * t;
    }
    red[tid] = v;
    __syncthreads();
    for (int t = 128; t > 0; t >>= 1) {
        if (tid < t) red[tid] += red[tid + t];
        __syncthreads();
    }
    const float r = rsqrtf(red[0] * (1.f / D_) + EPS_);

    for (int i = tid; i < D_; i += 256) {
        float o = (x[i] - mu) * r * gamma[i] + beta[i];
        out[(size_t)row * D_ + i] = o;
    }
}

// ---------------------------------------------------------------------------
extern "C" void kernel_launch(void* const* d_in, const int* in_sizes, int n_in,
                              void* d_out, int out_size, void* d_ws, size_t ws_size,
                              hipStream_t stream)
{
    const float* query = (const float*)d_in[0];
    const float* key   = (const float*)d_in[1];
    const float* value = (const float*)d_in[2];
    // d_in[3] = mask (causal) — applied structurally in attn_kernel
    const float* wq_w = (const float*)d_in[4];
    const float* wq_b = (const float*)d_in[5];
    const float* wk_w = (const float*)d_in[6];
    const float* wk_b = (const float*)d_in[7];
    const float* wv_w = (const float*)d_in[8];
    const float* wv_b = (const float*)d_in[9];
    const float* wo_w = (const float*)d_in[10];
    const float* wo_b = (const float*)d_in[11];
    const float* ln_g = (const float*)d_in[12];
    const float* ln_b = (const float*)d_in[13];

    float* out_f  = (float*)d_out;                        // (B,S,D)
    float* attn_f = out_f + (size_t)B_ * S_ * D_;         // (B,H,S,S)

    const size_t MAT = (size_t)B_ * S_ * D_;  // 4,194,304 floats (16 MB)
    float* ws  = (float*)d_ws;
    float* Qf  = ws;            // dead after attn; reused for pre-LN
    float* Kf  = ws + MAT;
    float* Vf  = ws + 2 * MAT;
    float* ctx = ws + 3 * MAT;
    float* pre = Qf;            // alias: pre-LN buffer

    const int M = B_ * S_, N = D_, K = D_;
    dim3 gblk(16, 16);
    dim3 ggrd(N / 64, M / 64);

    hipLaunchKernelGGL(gemm_bias_kernel, ggrd, gblk, 0, stream,
                       query, wq_w, wq_b, (const float*)nullptr, Qf, M, N, K);
    hipLaunchKernelGGL(gemm_bias_kernel, ggrd, gblk, 0, stream,
                       key, wk_w, wk_b, (const float*)nullptr, Kf, M, N, K);
    hipLaunchKernelGGL(gemm_bias_kernel, ggrd, gblk, 0, stream,
                       value, wv_w, wv_b, (const float*)nullptr, Vf, M, N, K);

    dim3 agrd(S_, B_ * H_);
    hipLaunchKernelGGL(attn_kernel, agrd, dim3(256), 0, stream,
                       Qf, Kf, Vf, attn_f, ctx);

    hipLaunchKernelGGL(gemm_bias_kernel, ggrd, gblk, 0, stream,
                       ctx, wo_w, wo_b, query, pre, M, N, K);

    hipLaunchKernelGGL(ln_kernel, dim3(B_ * S_), dim3(256), 0, stream,
                       pre, ln_g, ln_b, out_f);
}